// Round 1
// baseline (330.785 us; speedup 1.0000x reference)
//
#include <hip/hip_runtime.h>

// GuidedAttentionLoss: out = sum_{b,i<To[b],j<Ti[b]} A[b,i,j] * (1 - exp(-(i - j/Ti*To)^2 / (2*sigma^2))) / B
// A: [B, T_out, T_in] fp32, T_in = 512 (hardcoded, power of 2), B from in_sizes[1].
// Memory-bound: skip rows with i>=To and float4s with j>=Ti entirely (saves ~44% of HBM traffic).

#define GAL_SIGMA 0.4f
#define GAL_TIN   512
#define GAL_NVEC  128   // T_in / 4

__global__ __launch_bounds__(256) void gal_main_kernel(
    const float* __restrict__ align,
    const int*   __restrict__ in_len,
    const int*   __restrict__ out_len,
    float*       __restrict__ partials,
    int n_rows, int T_out)
{
    const int lane = threadIdx.x & 63;
    const int wid  = threadIdx.x >> 6;
    const int waves_total = gridDim.x << 2;   // 4 waves per block
    const float cexp = -1.0f / (2.0f * GAL_SIGMA * GAL_SIGMA);

    float acc = 0.0f;

    for (int row = (blockIdx.x << 2) + wid; row < n_rows; row += waves_total) {
        const int b = row / T_out;
        const int i = row - b * T_out;
        const int To = out_len[b];
        if (i >= To) continue;                 // whole row is zero-weight: skip load
        const int Ti = in_len[b];
        const float fi    = (float)i;
        const float ratio = (float)To / (float)Ti;   // ej = j * (To/Ti)

        const float4* rowp = (const float4*)(align + (size_t)row * GAL_TIN);

        // lane handles vec indices {lane, lane+64}; j0 = 4*v increases with v,
        // so once j0 >= Ti all later vecs for this lane are invalid too.
        for (int v = lane; v < GAL_NVEC; v += 64) {
            const int j0 = v << 2;
            if (j0 >= Ti) break;               // skip tail load (j >= Ti => w = 0)
            const float4 a = rowp[v];

            {   // j0 + 0
                const float d = fi - (float)(j0 + 0) * ratio;
                acc += a.x * (1.0f - __expf(d * d * cexp));
            }
            if (j0 + 1 < Ti) {
                const float d = fi - (float)(j0 + 1) * ratio;
                acc += a.y * (1.0f - __expf(d * d * cexp));
            }
            if (j0 + 2 < Ti) {
                const float d = fi - (float)(j0 + 2) * ratio;
                acc += a.z * (1.0f - __expf(d * d * cexp));
            }
            if (j0 + 3 < Ti) {
                const float d = fi - (float)(j0 + 3) * ratio;
                acc += a.w * (1.0f - __expf(d * d * cexp));
            }
        }
    }

    // wave reduce (64 lanes)
    #pragma unroll
    for (int off = 32; off > 0; off >>= 1)
        acc += __shfl_down(acc, off, 64);

    __shared__ float smem[4];
    if (lane == 0) smem[wid] = acc;
    __syncthreads();
    if (threadIdx.x == 0)
        partials[blockIdx.x] = smem[0] + smem[1] + smem[2] + smem[3];
}

__global__ __launch_bounds__(256) void gal_reduce_kernel(
    const float* __restrict__ partials,
    float*       __restrict__ out,
    int n, float inv_B)
{
    float acc = 0.0f;
    for (int idx = threadIdx.x; idx < n; idx += 256)
        acc += partials[idx];

    #pragma unroll
    for (int off = 32; off > 0; off >>= 1)
        acc += __shfl_down(acc, off, 64);

    __shared__ float smem[4];
    const int lane = threadIdx.x & 63;
    const int wid  = threadIdx.x >> 6;
    if (lane == 0) smem[wid] = acc;
    __syncthreads();
    if (threadIdx.x == 0)
        out[0] = (smem[0] + smem[1] + smem[2] + smem[3]) * inv_B;
}

extern "C" void kernel_launch(void* const* d_in, const int* in_sizes, int n_in,
                              void* d_out, int out_size, void* d_ws, size_t ws_size,
                              hipStream_t stream) {
    const float* align  = (const float*)d_in[0];
    const int*   in_len = (const int*)d_in[1];   // input_lengths  [B]
    const int*   out_len= (const int*)d_in[2];   // output_lengths [B]
    float* out = (float*)d_out;
    float* partials = (float*)d_ws;

    const int B     = in_sizes[1];
    const int T_out = in_sizes[0] / (B * GAL_TIN);
    const int n_rows = B * T_out;

    int nblocks = 4096;
    const int max_blocks = (int)(ws_size / sizeof(float));
    if (nblocks > max_blocks) nblocks = max_blocks;

    gal_main_kernel<<<nblocks, 256, 0, stream>>>(align, in_len, out_len,
                                                 partials, n_rows, T_out);
    gal_reduce_kernel<<<1, 256, 0, stream>>>(partials, out, nblocks, 1.0f / (float)B);
}

// Round 3
// 316.817 us; speedup vs baseline: 1.0441x; 1.0441x over previous
//
#include <hip/hip_runtime.h>

// GuidedAttentionLoss: out = sum_{b, i<To[b], j<Ti[b]} A[b,i,j] * (1 - exp(-(i - j*To/Ti)^2 / (2*sigma^2))) / B
// A: [B, T_out, T_in] fp32, T_in = 512. HBM-bound streaming reduction.
// R1/R2: LDS-cached lengths, two up-front float4 loads per row (2x MLP),
// nontemporal loads (streamed data, no reuse) via native ext_vector_type
// (HIP_vector_type<float,4> is a struct — rejected by the builtin).

#define GAL_SIGMA 0.4f
#define GAL_TIN   512
#define GAL_BMAX  256   // LDS length-cache capacity (B=64 in practice)

typedef float vfloat4 __attribute__((ext_vector_type(4)));

__global__ __launch_bounds__(256) void gal_main_kernel(
    const float* __restrict__ align,
    const int*   __restrict__ in_len,
    const int*   __restrict__ out_len,
    float*       __restrict__ partials,
    int n_rows, int T_out, int B)
{
    const int lane = threadIdx.x & 63;
    const int wid  = threadIdx.x >> 6;
    const int waves_total = gridDim.x << 2;   // 4 waves per block
    const float cexp = -1.0f / (2.0f * GAL_SIGMA * GAL_SIGMA);

    // Per-block cache of lengths and ratios: removes a dependent global load
    // from every row's critical path.
    __shared__ int   sTo[GAL_BMAX];
    __shared__ int   sTi[GAL_BMAX];
    __shared__ float sRatio[GAL_BMAX];
    for (int t = threadIdx.x; t < B && t < GAL_BMAX; t += 256) {
        const int ti = in_len[t];
        const int to = out_len[t];
        sTi[t] = ti; sTo[t] = to;
        sRatio[t] = (float)to / (float)ti;
    }
    __syncthreads();

    float acc = 0.0f;

    const int j0a = lane << 2;          // 0..252   (first half of row)
    const int j0b = 256 + (lane << 2);  // 256..508 (second half)

    for (int row = (blockIdx.x << 2) + wid; row < n_rows; row += waves_total) {
        const int b = row / T_out;
        const int i = row - b * T_out;
        const int To = (b < GAL_BMAX) ? sTo[b] : out_len[b];
        if (i >= To) continue;                 // whole row zero-weight: skip all loads
        const int   Ti    = (b < GAL_BMAX) ? sTi[b]    : in_len[b];
        const float ratio = (b < GAL_BMAX) ? sRatio[b] : ((float)To / (float)Ti);
        const float fi    = (float)i;

        const vfloat4* rowp = (const vfloat4*)(align + (size_t)row * GAL_TIN);

        // Issue both halves' loads up front (independent, 2x in-flight).
        const bool v0 = j0a < Ti;   // true in practice (Ti >= 256)
        const bool v1 = j0b < Ti;
        vfloat4 a0 = {0.f, 0.f, 0.f, 0.f}, a1 = {0.f, 0.f, 0.f, 0.f};
        if (v0) a0 = __builtin_nontemporal_load(rowp + lane);
        if (v1) a1 = __builtin_nontemporal_load(rowp + lane + 64);

        if (v0) {
            #pragma unroll
            for (int e = 0; e < 4; ++e) {
                const int j = j0a + e;
                const float d = fi - (float)j * ratio;
                const float w = 1.0f - __expf(d * d * cexp);
                acc += (j < Ti) ? a0[e] * w : 0.0f;
            }
        }
        if (v1) {
            #pragma unroll
            for (int e = 0; e < 4; ++e) {
                const int j = j0b + e;
                const float d = fi - (float)j * ratio;
                const float w = 1.0f - __expf(d * d * cexp);
                acc += (j < Ti) ? a1[e] * w : 0.0f;
            }
        }
    }

    // wave reduce (64 lanes)
    #pragma unroll
    for (int off = 32; off > 0; off >>= 1)
        acc += __shfl_down(acc, off, 64);

    __shared__ float smem[4];
    if (lane == 0) smem[wid] = acc;
    __syncthreads();
    if (threadIdx.x == 0)
        partials[blockIdx.x] = smem[0] + smem[1] + smem[2] + smem[3];
}

__global__ __launch_bounds__(256) void gal_reduce_kernel(
    const float* __restrict__ partials,
    float*       __restrict__ out,
    int n, float inv_B)
{
    float acc = 0.0f;
    for (int idx = threadIdx.x; idx < n; idx += 256)
        acc += partials[idx];

    #pragma unroll
    for (int off = 32; off > 0; off >>= 1)
        acc += __shfl_down(acc, off, 64);

    __shared__ float smem[4];
    const int lane = threadIdx.x & 63;
    const int wid  = threadIdx.x >> 6;
    if (lane == 0) smem[wid] = acc;
    __syncthreads();
    if (threadIdx.x == 0)
        out[0] = (smem[0] + smem[1] + smem[2] + smem[3]) * inv_B;
}

extern "C" void kernel_launch(void* const* d_in, const int* in_sizes, int n_in,
                              void* d_out, int out_size, void* d_ws, size_t ws_size,
                              hipStream_t stream) {
    const float* align   = (const float*)d_in[0];
    const int*   in_len  = (const int*)d_in[1];   // input_lengths  [B]
    const int*   out_len = (const int*)d_in[2];   // output_lengths [B]
    float* out = (float*)d_out;
    float* partials = (float*)d_ws;

    const int B      = in_sizes[1];
    const int T_out  = in_sizes[0] / (B * GAL_TIN);
    const int n_rows = B * T_out;

    int nblocks = 4096;
    const int max_blocks = (int)(ws_size / sizeof(float));
    if (nblocks > max_blocks) nblocks = max_blocks;

    gal_main_kernel<<<nblocks, 256, 0, stream>>>(align, in_len, out_len,
                                                 partials, n_rows, T_out, B);
    gal_reduce_kernel<<<1, 256, 0, stream>>>(partials, out, nblocks, 1.0f / (float)B);
}